// Round 16
// baseline (380.848 us; speedup 1.0000x reference)
//
#include <hip/hip_runtime.h>
#include <hip/hip_bf16.h>

#define BATCH 4096

typedef __attribute__((ext_vector_type(8))) short short8;
typedef __attribute__((ext_vector_type(16))) float f32x16;

// ---------------- d_ws layout (bf16 elems): weights only ----------------
#define WB1_ELEM 0
#define WB2_ELEM 512
#define WB3_ELEM 5120
#define WB4_ELEM 23552
#define WB_TOTAL 97280

// ---------------- fused-kernel LDS layout (bytes) ----------------
// sb   @0      : padded board bf16 [34][34]          2312 (pad 2320)
// a1   @2320   : borderless 32x32 px * 32B, swz key=((col>>2)&1)<<4   32768
// zs1  @35088  : 64B zero slot (conv2 OOB reads)
// a2   @35152  : borderless 16x16 px * 64B, swz key=((r+2c)&3)<<4     16384
// zs2  @51536  : 64B zero slot (conv3 OOB reads)     -> total 51600
// a3   @0      : 8x8 px * 128B, swz key=((r+2c)&7)<<4 (overlaps sb/a1)
// zs3  @8192   : 128B zero slot
// meanv@8320   : f32[128];  meanp @8832 : f32[2][128]
#define A1_OFF 2320
#define ZS1_OFF 35088
#define A2_OFF 35152
#define ZS2_OFF 51536
#define SMEM_F 51600
#define ZS3_REL 8192
#define MEANV_OFF 8320
#define MEANP_OFF 8832

static __device__ __forceinline__ unsigned pack2(float a, float b) {
    __hip_bfloat16 lo = __float2bfloat16(a), hi = __float2bfloat16(b);
    unsigned short ul = *(unsigned short*)&lo, uh = *(unsigned short*)&hi;
    return ((unsigned)uh << 16) | ul;
}

static __device__ __forceinline__ void store_bf16(void* p, float v) {
    __hip_bfloat16 b = __float2bfloat16(v);
    *(unsigned short*)p = *(unsigned short*)&b;
}

// ---------------------------------------------------------------------------
// Weight repack (unchanged layouts).
// ---------------------------------------------------------------------------
__global__ void prepack_weights(const float* __restrict__ w1,
                                const float* __restrict__ w2,
                                const float* __restrict__ w3,
                                const float* __restrict__ w4,
                                __hip_bfloat16* __restrict__ wb) {
    int g = blockIdx.x * 256 + threadIdx.x;
    if (g < 512) {
        int oc = g >> 4, k = g & 15;
        float v = (oc < 16 && k < 9) ? w1[oc * 9 + k] : 0.f;
        wb[g] = __float2bfloat16(v);
    } else if (g < WB3_ELEM) {
        int gg = g - WB2_ELEM;
        int oc = gg / 144, r = gg - oc * 144, tap = r >> 4, ic = r & 15;
        wb[g] = __float2bfloat16(w2[oc * 144 + ic * 9 + tap]);
    } else if (g < WB4_ELEM) {
        int gg = g - WB3_ELEM;
        int oc = gg / 288, r = gg - oc * 288, tap = r >> 5, ic = r & 31;
        wb[g] = __float2bfloat16(w3[oc * 288 + ic * 9 + tap]);
    } else if (g < WB_TOTAL) {
        int gg = g - WB4_ELEM;
        int oc = gg / 576, r = gg - oc * 576, tap = r >> 6, ic = r & 63;
        wb[g] = __float2bfloat16(w4[oc * 576 + ic * 9 + tap]);
    }
}

// ---------------------------------------------------------------------------
// Fused CNN, 512 threads (8 waves), 3 blocks/CU -> 24 waves/CU.
// ---------------------------------------------------------------------------
__global__ __launch_bounds__(512, 6) void cnn_fused_kernel(
    const float* __restrict__ board,
    const float* __restrict__ b1, const float* __restrict__ b2,
    const float* __restrict__ b3, const float* __restrict__ b4,
    const float* __restrict__ pw, const float* __restrict__ pb,
    const __hip_bfloat16* __restrict__ wb,
    float* __restrict__ bf_out)
{
    __shared__ alignas(16) char smem[SMEM_F];
    unsigned short* sbu = (unsigned short*)smem;
    char* a1b = smem + A1_OFF;
    char* a3b = smem;                       // overlaps dead sb/a1 in phase 5+
    float* meanv = (float*)(smem + MEANV_OFF);
    float* meanp = (float*)(smem + MEANP_OFF);

    const int t = threadIdx.x;
    const int img = blockIdx.x;
    const int w = t >> 6;                   // wave 0..7
    const int l = t & 63;
    const int n = l & 31;
    const int h = l >> 5;

    const char* wb3 = (const char*)(wb + WB3_ELEM);
    const char* wb4 = (const char*)(wb + WB4_ELEM);

    // ---- P0: zero sb borders + zs1/zs2 ----
    {
        if (t < 132) {
            int i = t, row, col;
            if (i < 34)       { row = 0;  col = i; }
            else if (i < 68)  { row = 33; col = i - 34; }
            else if (i < 100) { row = i - 68 + 1;  col = 0; }
            else              { row = i - 100 + 1; col = 33; }
            sbu[row * 34 + col] = 0;
        }
        uint4 z; z.x = z.y = z.z = z.w = 0u;
        if (t >= 256 && t < 260) ((uint4*)(smem + ZS1_OFF))[t - 256] = z;
        else if (t >= 260 && t < 264) ((uint4*)(smem + ZS2_OFF))[t - 260] = z;
    }
    __syncthreads();

    // ---- P1: load board (f32 -> bf16, padded interior) ----
    {
        float2 v = ((const float2*)board)[img * 512 + t];
        const int p0 = t * 2;
        const int row = (p0 >> 5) + 1, col = (p0 & 31) + 1;
        unsigned short* d = sbu + row * 34 + col;
        __hip_bfloat16 x0 = __float2bfloat16(v.x), x1 = __float2bfloat16(v.y);
        d[0] = *(unsigned short*)&x0; d[1] = *(unsigned short*)&x1;
    }
    __syncthreads();

    // ---- P2: conv1 (MFMA, taps as K, weights as A): 1->16 -> a1 (swz) ----
    {
        const short8 A1 = *(const short8*)((const char*)wb + (n * 16 + h * 8) * 2);
        float b1s[8];
#pragma unroll
        for (int r = 0; r < 8; ++r) b1s[r] = b1[(r & 3) + 8 * (r >> 2) + 4 * h];
        const unsigned* sbw = (const unsigned*)smem;
#pragma unroll 1
        for (int yi = 0; yi < 4; ++yi) {
            const int y = 4 * w + yi;
            unsigned short c[3][3];
#pragma unroll
            for (int dy = 0; dy < 3; ++dy) {
                const int base = (y + dy) * 17 + (n >> 1);
                const unsigned w0 = sbw[base], w1v = sbw[base + 1];
                if (n & 1) {
                    c[dy][0] = (unsigned short)(w0 >> 16);
                    c[dy][1] = (unsigned short)(w1v & 0xffff);
                    c[dy][2] = (unsigned short)(w1v >> 16);
                } else {
                    c[dy][0] = (unsigned short)(w0 & 0xffff);
                    c[dy][1] = (unsigned short)(w0 >> 16);
                    c[dy][2] = (unsigned short)(w1v & 0xffff);
                }
            }
            short8 Bv;
            if (h == 0) {
                Bv[0] = (short)c[0][0]; Bv[1] = (short)c[0][1]; Bv[2] = (short)c[0][2];
                Bv[3] = (short)c[1][0]; Bv[4] = (short)c[1][1]; Bv[5] = (short)c[1][2];
                Bv[6] = (short)c[2][0]; Bv[7] = (short)c[2][1];
            } else {
                Bv = (short8)0;
                Bv[0] = (short)c[2][2];
            }
            f32x16 acc = __builtin_amdgcn_mfma_f32_32x32x16_bf16(A1, Bv, (f32x16)0.0f, 0, 0, 0);
            float v8[8];
#pragma unroll
            for (int r = 0; r < 8; ++r) v8[r] = fmaxf(acc[r] + b1s[r], 0.f);
            const int key = ((n >> 2) & 1) << 4;
            char* dst = a1b + (y * 32 + n) * 32;
            uint2 u0, u1;
            u0.x = pack2(v8[0], v8[1]); u0.y = pack2(v8[2], v8[3]);
            u1.x = pack2(v8[4], v8[5]); u1.y = pack2(v8[6], v8[7]);
            *(uint2*)(dst + ((h * 8) ^ key)) = u0;
            *(uint2*)(dst + ((h * 8 + 16) ^ key)) = u1;
        }
    }
    __syncthreads();

    // ---- P3: conv2 (pixels as A, predicated reads): 16->32,
    //          relu + in-lane 2x2 pool -> a2 (LDS) ----
    {
        const char* wb2 = (const char*)(wb + WB2_ELEM);
        const float biasv = b2[n];
        const int y_off = 2 * ((n >> 2) & 1) + ((n >> 1) & 1);
        const int x_off = 2 * ((n >> 3) & 3) + (n & 1);
        const int py_base = 2 * w;               // pooled rows 2w, 2w+1
        const int yb = 4 * w + y_off;

#pragma unroll 1
        for (int pxh = 0; pxh < 2; ++pxh) {
            const int x0 = 16 * pxh + x_off;
            f32x16 acc0 = (f32x16)0.0f, acc1 = (f32x16)0.0f;
#pragma unroll
            for (int tp = 0; tp < 9; ++tp) {
                const int dy = tp / 3, dx = tp - 3 * dy;
                short8 Bw = *(const short8*)(wb2 + (n * 144 + tp * 16 + h * 8) * 2);
                const int r_u = yb + dy - 1;
                const int c0 = x0 + dx - 1, c1 = x0 + 8 + dx - 1;
                const bool okr = (unsigned)r_u < 32u;
                const int off0 = (okr && (unsigned)c0 < 32u)
                    ? (A1_OFF + (r_u * 32 + c0) * 32 + ((h * 16) ^ (((c0 >> 2) & 1) << 4)))
                    : (ZS1_OFF + h * 16);
                const int off1 = (okr && (unsigned)c1 < 32u)
                    ? (A1_OFF + (r_u * 32 + c1) * 32 + ((h * 16) ^ (((c1 >> 2) & 1) << 4)))
                    : (ZS1_OFF + h * 16);
                short8 A0 = *(const short8*)(smem + off0);
                short8 A1v = *(const short8*)(smem + off1);
                acc0 = __builtin_amdgcn_mfma_f32_32x32x16_bf16(A0, Bw, acc0, 0, 0, 0);
                acc1 = __builtin_amdgcn_mfma_f32_32x32x16_bf16(A1v, Bw, acc1, 0, 0, 0);
            }
            const int py = py_base + h;
#pragma unroll
            for (int e = 0; e < 2; ++e) {
                const f32x16 acc = e ? acc1 : acc0;
                const int pxb = 2 * pxh + e;
#pragma unroll
                for (int j = 0; j < 4; ++j) {
                    float v = fmaxf(fmaxf(acc[4 * j], acc[4 * j + 1]),
                                    fmaxf(acc[4 * j + 2], acc[4 * j + 3]));
                    v = fmaxf(v + biasv, 0.f);
                    const int px = 4 * pxb + j;
                    const int key = (py + 2 * px) & 3;
                    store_bf16(smem + A2_OFF + (py * 16 + px) * 64 +
                               ((((n >> 3) ^ key) & 3) << 4) + ((n * 2) & 15), v);
                }
            }
        }
    }
    __syncthreads();

    // ---- P4: zero zs3 (a3 region now free) ----
    {
        uint4 z; z.x = z.y = z.z = z.w = 0u;
        if (t < 8) ((uint4*)(a3b + ZS3_REL))[t] = z;
    }
    __syncthreads();

    // ---- P5: conv3 (pixels as A): 32->64, relu + in-lane pool -> a3 ----
    {
        const int rg = w >> 1;                   // row-group 0..3
        const int pxh = w & 1;                   // x-half
        const int y_off = 2 * ((n >> 2) & 1) + ((n >> 1) & 1);
        const int x_off = 2 * ((n >> 3) & 3) + (n & 1) + 8 * pxh;
        const int y_in = 4 * rg + y_off;         // pre-pool row 0..15
        f32x16 acc0 = (f32x16)0.0f, acc1 = (f32x16)0.0f;   // ocb 0/1
#pragma unroll
        for (int step = 0; step < 18; ++step) {
            const int tp = step >> 1, kh = step & 1;
            const int dy = tp / 3, dx = tp - 3 * dy;
            short8 B0 = *(const short8*)(wb3 + ((n)      * 288 + tp * 32 + kh * 16 + h * 8) * 2);
            short8 B1 = *(const short8*)(wb3 + ((32 + n) * 288 + tp * 32 + kh * 16 + h * 8) * 2);
            const int row_u = y_in + dy - 1;
            const int col_u = x_off + dx - 1;
            const int sbase = kh * 32 + h * 16;
            const bool ok = ((unsigned)row_u < 16u) && ((unsigned)col_u < 16u);
            const int off = ok
                ? (A2_OFF + row_u * 1024 + col_u * 64 + (sbase ^ (((row_u + 2 * col_u) & 3) << 4)))
                : (ZS2_OFF + sbase);
            short8 A0 = *(const short8*)(smem + off);
            acc0 = __builtin_amdgcn_mfma_f32_32x32x16_bf16(A0, B0, acc0, 0, 0, 0);
            acc1 = __builtin_amdgcn_mfma_f32_32x32x16_bf16(A0, B1, acc1, 0, 0, 0);
        }
        const int py = 2 * rg + h;               // pooled row 0..7
#pragma unroll
        for (int e = 0; e < 2; ++e) {
            const f32x16 acc = e ? acc1 : acc0;
            const float biasv = b3[32 * e + n];
#pragma unroll
            for (int j = 0; j < 4; ++j) {
                float v = fmaxf(fmaxf(acc[4 * j], acc[4 * j + 1]),
                                fmaxf(acc[4 * j + 2], acc[4 * j + 3]));
                v = fmaxf(v + biasv, 0.f);
                const int px = 4 * pxh + j;      // pooled col 0..7
                const int byte_in = e * 64 + n * 2;
                const int key3 = (py + 2 * px) & 7;
                store_bf16(a3b + (py * 8 + px) * 128 +
                           ((((byte_in >> 4) ^ key3) << 4) | (byte_in & 15)), v);
            }
        }
    }
    __syncthreads();

    // ---- P6: conv4 (pixels as A): 64->128, relu + partial avg -> meanp ----
    {
        const int ocb4 = w >> 1;                 // oc-tile 0..3
        const int mt = w & 1;                    // pixel-row tile 0/1
        const int x4 = n & 7, y4 = (n >> 3) & 3;
        f32x16 a0 = (f32x16)0.0f;
#pragma unroll
        for (int dy = 0; dy < 3; ++dy)
#pragma unroll
            for (int dx = 0; dx < 3; ++dx) {
                const int row_m = 4 * mt + y4 + dy - 1;
                const int col_u = x4 + dx - 1;
                const bool ok = ((unsigned)col_u < 8u) && ((unsigned)row_m < 8u);
#pragma unroll
                for (int kc = 0; kc < 4; ++kc) {
                    const int s4 = kc * 32 + h * 16;
                    const int off = ok
                        ? ((row_m * 8 + col_u) * 128 + (s4 ^ (((row_m + 2 * col_u) & 7) << 4)))
                        : (ZS3_REL + s4);
                    short8 B = *(const short8*)(wb4 + ((32 * ocb4 + n) * 576 + (dy * 3 + dx) * 64 + kc * 16 + h * 8) * 2);
                    short8 A0 = *(const short8*)(a3b + off);
                    a0 = __builtin_amdgcn_mfma_f32_32x32x16_bf16(A0, B, a0, 0, 0, 0);
                }
            }
        const float biasv = b4[32 * ocb4 + n];
        float s = 0.f;
#pragma unroll
        for (int r = 0; r < 16; ++r) s += fmaxf(a0[r] + biasv, 0.f);
        s += __shfl_xor(s, 32);
        if (l < 32) meanp[mt * 128 + 32 * ocb4 + l] = s;
    }
    __syncthreads();

    // ---- P6b: combine meanp halves ----
    if (t < 128) meanv[t] = (meanp[t] + meanp[128 + t]) * (1.f / 64.f);
    __syncthreads();

    // ---- P7: proj (VALU, 256 threads, k-split) ----
    if (t < 256) {
        const int o = t >> 1, kh = t & 1;
        const float* wrow = pw + o * 128 + kh * 64;
        const float* mv = meanv + kh * 64;
        float acc = 0.f;
        for (int k = 0; k < 64; ++k) acc = fmaf(mv[k], wrow[k], acc);
        acc += __shfl_xor(acc, 1);
        if (kh == 0) bf_out[img * 128 + o] = acc + pb[o];
    }
}

// ---------------------------------------------------------------------------
// Kernel C: GRU step + head (unchanged).
// ---------------------------------------------------------------------------
__global__ __launch_bounds__(384) void gru_kernel(
    const float* __restrict__ hin,
    const int* __restrict__ atok, const int* __restrict__ uidx,
    const float* __restrict__ emb,
    const float* __restrict__ w_ih, const float* __restrict__ w_hh,
    const float* __restrict__ b_ih, const float* __restrict__ b_hh,
    const float* __restrict__ head_w, const float* __restrict__ head_b,
    float* __restrict__ out)
{
    const int img0 = blockIdx.x * 8;
    const int t = threadIdx.x;
    __shared__ float xin_s[8][168];
    __shared__ float h0_s[8][128];
    __shared__ float gis[8][384];
    __shared__ float ghs[8][384];
    __shared__ float hn_s[8][128];
    const float* bf = out + BATCH * 6;

    for (int idx = t; idx < 8 * 168; idx += 384) {
        const int r = idx / 168, k = idx - r * 168;
        const int row = img0 + r;
        float v;
        if (k < 128)      v = bf[row * 128 + k];
        else if (k < 136) v = (float)((atok[row] >> (k - 128)) & 1);
        else              v = emb[uidx[row] * 32 + (k - 136)];
        xin_s[r][k] = v;
    }
    for (int idx = t; idx < 8 * 128; idx += 384) {
        const int r = idx >> 7, k = idx & 127;
        h0_s[r][k] = hin[(img0 + r) * 128 + k];
    }
    __syncthreads();

    {
        const int o = t;
        float gi[8], gh[8];
        const float bi = b_ih[o], bh = b_hh[o];
#pragma unroll
        for (int r = 0; r < 8; ++r) { gi[r] = bi; gh[r] = bh; }
        const float* wi = w_ih + o * 168;
        const float* wh = w_hh + o * 128;
        for (int k = 0; k < 128; ++k) {
            const float wv = wi[k];
            const float wvh = wh[k];
#pragma unroll
            for (int r = 0; r < 8; ++r) {
                gi[r] = fmaf(wv, xin_s[r][k], gi[r]);
                gh[r] = fmaf(wvh, h0_s[r][k], gh[r]);
            }
        }
        for (int k = 128; k < 168; ++k) {
            const float wv = wi[k];
#pragma unroll
            for (int r = 0; r < 8; ++r) gi[r] = fmaf(wv, xin_s[r][k], gi[r]);
        }
#pragma unroll
        for (int r = 0; r < 8; ++r) { gis[r][o] = gi[r]; ghs[r][o] = gh[r]; }
    }
    __syncthreads();

    if (t < 128) {
#pragma unroll
        for (int r = 0; r < 8; ++r) {
            const float rg = 1.f / (1.f + expf(-(gis[r][t] + ghs[r][t])));
            const float z  = 1.f / (1.f + expf(-(gis[r][128 + t] + ghs[r][128 + t])));
            const float nn = tanhf(gis[r][256 + t] + rg * ghs[r][256 + t]);
            const float hn = (1.f - z) * nn + z * h0_s[r][t];
            hn_s[r][t] = hn;
            out[BATCH * 6 + (img0 + r) * 128 + t] = hn;
        }
    }
    __syncthreads();

    if (t < 48) {
        const int r = t / 6, j = t - r * 6;
        float acc = head_b[j];
        const float* wrow = head_w + j * 128;
        for (int k = 0; k < 128; ++k) acc = fmaf(hn_s[r][k], wrow[k], acc);
        out[(img0 + r) * 6 + j] = acc;
    }
}

extern "C" void kernel_launch(void* const* d_in, const int* in_sizes, int n_in,
                              void* d_out, int out_size, void* d_ws, size_t ws_size,
                              hipStream_t stream) {
    const float* board = (const float*)d_in[0];
    const float* h     = (const float*)d_in[1];
    const int*   atok  = (const int*)d_in[2];
    const int*   uidx  = (const int*)d_in[3];
    const float* w1 = (const float*)d_in[4];
    const float* b1 = (const float*)d_in[5];
    const float* w2 = (const float*)d_in[6];
    const float* b2 = (const float*)d_in[7];
    const float* w3 = (const float*)d_in[8];
    const float* b3 = (const float*)d_in[9];
    const float* w4 = (const float*)d_in[10];
    const float* b4 = (const float*)d_in[11];
    const float* pw = (const float*)d_in[12];
    const float* pb = (const float*)d_in[13];
    const float* emb  = (const float*)d_in[14];
    const float* w_ih = (const float*)d_in[15];
    const float* w_hh = (const float*)d_in[16];
    const float* b_ih = (const float*)d_in[17];
    const float* b_hh = (const float*)d_in[18];
    const float* head_w = (const float*)d_in[19];
    const float* head_b = (const float*)d_in[20];
    float* out = (float*)d_out;
    __hip_bfloat16* wb = (__hip_bfloat16*)d_ws;

    float* bf = out + BATCH * 6;
    prepack_weights<<<(WB_TOTAL + 255) / 256, 256, 0, stream>>>(w1, w2, w3, w4, wb);
    cnn_fused_kernel<<<BATCH, 512, 0, stream>>>(board, b1, b2, b3, b4,
                                                pw, pb, wb, bf);
    gru_kernel<<<BATCH / 8, 384, 0, stream>>>(h, atok, uidx, emb, w_ih, w_hh,
                                              b_ih, b_hh, head_w, head_b, out);
}

// Round 17
// 308.208 us; speedup vs baseline: 1.2357x; 1.2357x over previous
//
#include <hip/hip_runtime.h>
#include <hip/hip_bf16.h>

#define BATCH 4096

typedef __attribute__((ext_vector_type(8))) short short8;
typedef __attribute__((ext_vector_type(16))) float f32x16;

// ---------------- d_ws layout (bf16 elems): weights only ----------------
#define WB1_ELEM 0
#define WB2_ELEM 512
#define WB3_ELEM 5120
#define WB4_ELEM 23552
#define WB_TOTAL 97280

// ---------------- fused-kernel LDS layout (bytes) ----------------
#define A1_OFF 2320
#define ZS1_OFF 35088
#define A2_OFF 35152
#define ZS2_OFF 51536
#define SMEM_F 51600
#define ZS3_REL 8192
#define MEANV_OFF 8320
#define MEANP_OFF 8832

static __device__ __forceinline__ unsigned pack2(float a, float b) {
    __hip_bfloat16 lo = __float2bfloat16(a), hi = __float2bfloat16(b);
    unsigned short ul = *(unsigned short*)&lo, uh = *(unsigned short*)&hi;
    return ((unsigned)uh << 16) | ul;
}

static __device__ __forceinline__ void store_bf16(void* p, float v) {
    __hip_bfloat16 b = __float2bfloat16(v);
    *(unsigned short*)p = *(unsigned short*)&b;
}

// ---------------------------------------------------------------------------
// Weight repack (unchanged layouts).
// ---------------------------------------------------------------------------
__global__ void prepack_weights(const float* __restrict__ w1,
                                const float* __restrict__ w2,
                                const float* __restrict__ w3,
                                const float* __restrict__ w4,
                                __hip_bfloat16* __restrict__ wb) {
    int g = blockIdx.x * 256 + threadIdx.x;
    if (g < 512) {
        int oc = g >> 4, k = g & 15;
        float v = (oc < 16 && k < 9) ? w1[oc * 9 + k] : 0.f;
        wb[g] = __float2bfloat16(v);
    } else if (g < WB3_ELEM) {
        int gg = g - WB2_ELEM;
        int oc = gg / 144, r = gg - oc * 144, tap = r >> 4, ic = r & 15;
        wb[g] = __float2bfloat16(w2[oc * 144 + ic * 9 + tap]);
    } else if (g < WB4_ELEM) {
        int gg = g - WB3_ELEM;
        int oc = gg / 288, r = gg - oc * 288, tap = r >> 5, ic = r & 31;
        wb[g] = __float2bfloat16(w3[oc * 288 + ic * 9 + tap]);
    } else if (g < WB_TOTAL) {
        int gg = g - WB4_ELEM;
        int oc = gg / 576, r = gg - oc * 576, tap = r >> 6, ic = r & 63;
        wb[g] = __float2bfloat16(w4[oc * 576 + ic * 9 + tap]);
    }
}

// ---------------------------------------------------------------------------
// Fused CNN, 512 threads (8 waves), launch_bounds(512,4): VGPR cap 128,
// 2 blocks/CU -> 16 waves/CU, no spill.
// ---------------------------------------------------------------------------
__global__ __launch_bounds__(512, 4) void cnn_fused_kernel(
    const float* __restrict__ board,
    const float* __restrict__ b1, const float* __restrict__ b2,
    const float* __restrict__ b3, const float* __restrict__ b4,
    const float* __restrict__ pw, const float* __restrict__ pb,
    const __hip_bfloat16* __restrict__ wb,
    float* __restrict__ bf_out)
{
    __shared__ alignas(16) char smem[SMEM_F];
    unsigned short* sbu = (unsigned short*)smem;
    char* a1b = smem + A1_OFF;
    char* a3b = smem;                       // overlaps dead sb/a1 in phase 5+
    float* meanv = (float*)(smem + MEANV_OFF);
    float* meanp = (float*)(smem + MEANP_OFF);

    const int t = threadIdx.x;
    const int img = blockIdx.x;
    const int w = t >> 6;                   // wave 0..7
    const int l = t & 63;
    const int n = l & 31;
    const int h = l >> 5;

    const char* wb3 = (const char*)(wb + WB3_ELEM);
    const char* wb4 = (const char*)(wb + WB4_ELEM);

    // ---- P0: zero sb borders + zs1/zs2 ----
    {
        if (t < 132) {
            int i = t, row, col;
            if (i < 34)       { row = 0;  col = i; }
            else if (i < 68)  { row = 33; col = i - 34; }
            else if (i < 100) { row = i - 68 + 1;  col = 0; }
            else              { row = i - 100 + 1; col = 33; }
            sbu[row * 34 + col] = 0;
        }
        uint4 z; z.x = z.y = z.z = z.w = 0u;
        if (t >= 256 && t < 260) ((uint4*)(smem + ZS1_OFF))[t - 256] = z;
        else if (t >= 260 && t < 264) ((uint4*)(smem + ZS2_OFF))[t - 260] = z;
    }
    __syncthreads();

    // ---- P1: load board (f32 -> bf16, padded interior) ----
    {
        float2 v = ((const float2*)board)[img * 512 + t];
        const int p0 = t * 2;
        const int row = (p0 >> 5) + 1, col = (p0 & 31) + 1;
        unsigned short* d = sbu + row * 34 + col;
        __hip_bfloat16 x0 = __float2bfloat16(v.x), x1 = __float2bfloat16(v.y);
        d[0] = *(unsigned short*)&x0; d[1] = *(unsigned short*)&x1;
    }
    __syncthreads();

    // ---- P2: conv1 (MFMA, taps as K, weights as A): 1->16 -> a1 (swz) ----
    {
        const short8 A1 = *(const short8*)((const char*)wb + (n * 16 + h * 8) * 2);
        float b1s[8];
#pragma unroll
        for (int r = 0; r < 8; ++r) b1s[r] = b1[(r & 3) + 8 * (r >> 2) + 4 * h];
        const unsigned* sbw = (const unsigned*)smem;
#pragma unroll 1
        for (int yi = 0; yi < 4; ++yi) {
            const int y = 4 * w + yi;
            unsigned short c[3][3];
#pragma unroll
            for (int dy = 0; dy < 3; ++dy) {
                const int base = (y + dy) * 17 + (n >> 1);
                const unsigned w0 = sbw[base], w1v = sbw[base + 1];
                if (n & 1) {
                    c[dy][0] = (unsigned short)(w0 >> 16);
                    c[dy][1] = (unsigned short)(w1v & 0xffff);
                    c[dy][2] = (unsigned short)(w1v >> 16);
                } else {
                    c[dy][0] = (unsigned short)(w0 & 0xffff);
                    c[dy][1] = (unsigned short)(w0 >> 16);
                    c[dy][2] = (unsigned short)(w1v & 0xffff);
                }
            }
            short8 Bv;
            if (h == 0) {
                Bv[0] = (short)c[0][0]; Bv[1] = (short)c[0][1]; Bv[2] = (short)c[0][2];
                Bv[3] = (short)c[1][0]; Bv[4] = (short)c[1][1]; Bv[5] = (short)c[1][2];
                Bv[6] = (short)c[2][0]; Bv[7] = (short)c[2][1];
            } else {
                Bv = (short8)0;
                Bv[0] = (short)c[2][2];
            }
            f32x16 acc = __builtin_amdgcn_mfma_f32_32x32x16_bf16(A1, Bv, (f32x16)0.0f, 0, 0, 0);
            float v8[8];
#pragma unroll
            for (int r = 0; r < 8; ++r) v8[r] = fmaxf(acc[r] + b1s[r], 0.f);
            const int key = ((n >> 2) & 1) << 4;
            char* dst = a1b + (y * 32 + n) * 32;
            uint2 u0, u1;
            u0.x = pack2(v8[0], v8[1]); u0.y = pack2(v8[2], v8[3]);
            u1.x = pack2(v8[4], v8[5]); u1.y = pack2(v8[6], v8[7]);
            *(uint2*)(dst + ((h * 8) ^ key)) = u0;
            *(uint2*)(dst + ((h * 8 + 16) ^ key)) = u1;
        }
    }
    __syncthreads();

    // ---- P3: conv2 (pixels as A, predicated reads): 16->32,
    //          relu + in-lane 2x2 pool -> a2 (LDS) ----
    {
        const char* wb2 = (const char*)(wb + WB2_ELEM);
        const float biasv = b2[n];
        const int y_off = 2 * ((n >> 2) & 1) + ((n >> 1) & 1);
        const int x_off = 2 * ((n >> 3) & 3) + (n & 1);
        const int py_base = 2 * w;               // pooled rows 2w, 2w+1
        const int yb = 4 * w + y_off;

#pragma unroll 1
        for (int pxh = 0; pxh < 2; ++pxh) {
            const int x0 = 16 * pxh + x_off;
            f32x16 acc0 = (f32x16)0.0f, acc1 = (f32x16)0.0f;
#pragma unroll
            for (int tp = 0; tp < 9; ++tp) {
                const int dy = tp / 3, dx = tp - 3 * dy;
                short8 Bw = *(const short8*)(wb2 + (n * 144 + tp * 16 + h * 8) * 2);
                const int r_u = yb + dy - 1;
                const int c0 = x0 + dx - 1, c1 = x0 + 8 + dx - 1;
                const bool okr = (unsigned)r_u < 32u;
                const int off0 = (okr && (unsigned)c0 < 32u)
                    ? (A1_OFF + (r_u * 32 + c0) * 32 + ((h * 16) ^ (((c0 >> 2) & 1) << 4)))
                    : (ZS1_OFF + h * 16);
                const int off1 = (okr && (unsigned)c1 < 32u)
                    ? (A1_OFF + (r_u * 32 + c1) * 32 + ((h * 16) ^ (((c1 >> 2) & 1) << 4)))
                    : (ZS1_OFF + h * 16);
                short8 A0 = *(const short8*)(smem + off0);
                short8 A1v = *(const short8*)(smem + off1);
                acc0 = __builtin_amdgcn_mfma_f32_32x32x16_bf16(A0, Bw, acc0, 0, 0, 0);
                acc1 = __builtin_amdgcn_mfma_f32_32x32x16_bf16(A1v, Bw, acc1, 0, 0, 0);
            }
            const int py = py_base + h;
#pragma unroll
            for (int e = 0; e < 2; ++e) {
                const f32x16 acc = e ? acc1 : acc0;
                const int pxb = 2 * pxh + e;
#pragma unroll
                for (int j = 0; j < 4; ++j) {
                    float v = fmaxf(fmaxf(acc[4 * j], acc[4 * j + 1]),
                                    fmaxf(acc[4 * j + 2], acc[4 * j + 3]));
                    v = fmaxf(v + biasv, 0.f);
                    const int px = 4 * pxb + j;
                    const int key = (py + 2 * px) & 3;
                    store_bf16(smem + A2_OFF + (py * 16 + px) * 64 +
                               ((((n >> 3) ^ key) & 3) << 4) + ((n * 2) & 15), v);
                }
            }
        }
    }
    __syncthreads();

    // ---- P4: zero zs3 (a3 region now free) ----
    {
        uint4 z; z.x = z.y = z.z = z.w = 0u;
        if (t < 8) ((uint4*)(a3b + ZS3_REL))[t] = z;
    }
    __syncthreads();

    // ---- P5: conv3 (pixels as A): 32->64, relu + in-lane pool -> a3 ----
    {
        const int rg = w >> 1;                   // row-group 0..3
        const int pxh = w & 1;                   // x-half
        const int y_off = 2 * ((n >> 2) & 1) + ((n >> 1) & 1);
        const int x_off = 2 * ((n >> 3) & 3) + (n & 1) + 8 * pxh;
        const int y_in = 4 * rg + y_off;         // pre-pool row 0..15
        f32x16 acc0 = (f32x16)0.0f, acc1 = (f32x16)0.0f;   // ocb 0/1
#pragma unroll
        for (int step = 0; step < 18; ++step) {
            const int tp = step >> 1, kh = step & 1;
            const int dy = tp / 3, dx = tp - 3 * dy;
            short8 B0 = *(const short8*)(wb3 + ((n)      * 288 + tp * 32 + kh * 16 + h * 8) * 2);
            short8 B1 = *(const short8*)(wb3 + ((32 + n) * 288 + tp * 32 + kh * 16 + h * 8) * 2);
            const int row_u = y_in + dy - 1;
            const int col_u = x_off + dx - 1;
            const int sbase = kh * 32 + h * 16;
            const bool ok = ((unsigned)row_u < 16u) && ((unsigned)col_u < 16u);
            const int off = ok
                ? (A2_OFF + row_u * 1024 + col_u * 64 + (sbase ^ (((row_u + 2 * col_u) & 3) << 4)))
                : (ZS2_OFF + sbase);
            short8 A0 = *(const short8*)(smem + off);
            acc0 = __builtin_amdgcn_mfma_f32_32x32x16_bf16(A0, B0, acc0, 0, 0, 0);
            acc1 = __builtin_amdgcn_mfma_f32_32x32x16_bf16(A0, B1, acc1, 0, 0, 0);
        }
        const int py = 2 * rg + h;               // pooled row 0..7
#pragma unroll
        for (int e = 0; e < 2; ++e) {
            const f32x16 acc = e ? acc1 : acc0;
            const float biasv = b3[32 * e + n];
#pragma unroll
            for (int j = 0; j < 4; ++j) {
                float v = fmaxf(fmaxf(acc[4 * j], acc[4 * j + 1]),
                                fmaxf(acc[4 * j + 2], acc[4 * j + 3]));
                v = fmaxf(v + biasv, 0.f);
                const int px = 4 * pxh + j;      // pooled col 0..7
                const int byte_in = e * 64 + n * 2;
                const int key3 = (py + 2 * px) & 7;
                store_bf16(a3b + (py * 8 + px) * 128 +
                           ((((byte_in >> 4) ^ key3) << 4) | (byte_in & 15)), v);
            }
        }
    }
    __syncthreads();

    // ---- P6: conv4 (pixels as A): 64->128, relu + partial avg -> meanp ----
    {
        const int ocb4 = w >> 1;                 // oc-tile 0..3
        const int mt = w & 1;                    // pixel-row tile 0/1
        const int x4 = n & 7, y4 = (n >> 3) & 3;
        f32x16 a0 = (f32x16)0.0f;
#pragma unroll
        for (int dy = 0; dy < 3; ++dy)
#pragma unroll
            for (int dx = 0; dx < 3; ++dx) {
                const int row_m = 4 * mt + y4 + dy - 1;
                const int col_u = x4 + dx - 1;
                const bool ok = ((unsigned)col_u < 8u) && ((unsigned)row_m < 8u);
#pragma unroll
                for (int kc = 0; kc < 4; ++kc) {
                    const int s4 = kc * 32 + h * 16;
                    const int off = ok
                        ? ((row_m * 8 + col_u) * 128 + (s4 ^ (((row_m + 2 * col_u) & 7) << 4)))
                        : (ZS3_REL + s4);
                    short8 B = *(const short8*)(wb4 + ((32 * ocb4 + n) * 576 + (dy * 3 + dx) * 64 + kc * 16 + h * 8) * 2);
                    short8 A0 = *(const short8*)(a3b + off);
                    a0 = __builtin_amdgcn_mfma_f32_32x32x16_bf16(A0, B, a0, 0, 0, 0);
                }
            }
        const float biasv = b4[32 * ocb4 + n];
        float s = 0.f;
#pragma unroll
        for (int r = 0; r < 16; ++r) s += fmaxf(a0[r] + biasv, 0.f);
        s += __shfl_xor(s, 32);
        if (l < 32) meanp[mt * 128 + 32 * ocb4 + l] = s;
    }
    __syncthreads();

    // ---- P6b: combine meanp halves ----
    if (t < 128) meanv[t] = (meanp[t] + meanp[128 + t]) * (1.f / 64.f);
    __syncthreads();

    // ---- P7: proj (VALU, 256 threads, k-split) ----
    if (t < 256) {
        const int o = t >> 1, kh = t & 1;
        const float* wrow = pw + o * 128 + kh * 64;
        const float* mv = meanv + kh * 64;
        float acc = 0.f;
        for (int k = 0; k < 64; ++k) acc = fmaf(mv[k], wrow[k], acc);
        acc += __shfl_xor(acc, 1);
        if (kh == 0) bf_out[img * 128 + o] = acc + pb[o];
    }
}

// ---------------------------------------------------------------------------
// Kernel C: GRU step + head (unchanged).
// ---------------------------------------------------------------------------
__global__ __launch_bounds__(384) void gru_kernel(
    const float* __restrict__ hin,
    const int* __restrict__ atok, const int* __restrict__ uidx,
    const float* __restrict__ emb,
    const float* __restrict__ w_ih, const float* __restrict__ w_hh,
    const float* __restrict__ b_ih, const float* __restrict__ b_hh,
    const float* __restrict__ head_w, const float* __restrict__ head_b,
    float* __restrict__ out)
{
    const int img0 = blockIdx.x * 8;
    const int t = threadIdx.x;
    __shared__ float xin_s[8][168];
    __shared__ float h0_s[8][128];
    __shared__ float gis[8][384];
    __shared__ float ghs[8][384];
    __shared__ float hn_s[8][128];
    const float* bf = out + BATCH * 6;

    for (int idx = t; idx < 8 * 168; idx += 384) {
        const int r = idx / 168, k = idx - r * 168;
        const int row = img0 + r;
        float v;
        if (k < 128)      v = bf[row * 128 + k];
        else if (k < 136) v = (float)((atok[row] >> (k - 128)) & 1);
        else              v = emb[uidx[row] * 32 + (k - 136)];
        xin_s[r][k] = v;
    }
    for (int idx = t; idx < 8 * 128; idx += 384) {
        const int r = idx >> 7, k = idx & 127;
        h0_s[r][k] = hin[(img0 + r) * 128 + k];
    }
    __syncthreads();

    {
        const int o = t;
        float gi[8], gh[8];
        const float bi = b_ih[o], bh = b_hh[o];
#pragma unroll
        for (int r = 0; r < 8; ++r) { gi[r] = bi; gh[r] = bh; }
        const float* wi = w_ih + o * 168;
        const float* wh = w_hh + o * 128;
        for (int k = 0; k < 128; ++k) {
            const float wv = wi[k];
            const float wvh = wh[k];
#pragma unroll
            for (int r = 0; r < 8; ++r) {
                gi[r] = fmaf(wv, xin_s[r][k], gi[r]);
                gh[r] = fmaf(wvh, h0_s[r][k], gh[r]);
            }
        }
        for (int k = 128; k < 168; ++k) {
            const float wv = wi[k];
#pragma unroll
            for (int r = 0; r < 8; ++r) gi[r] = fmaf(wv, xin_s[r][k], gi[r]);
        }
#pragma unroll
        for (int r = 0; r < 8; ++r) { gis[r][o] = gi[r]; ghs[r][o] = gh[r]; }
    }
    __syncthreads();

    if (t < 128) {
#pragma unroll
        for (int r = 0; r < 8; ++r) {
            const float rg = 1.f / (1.f + expf(-(gis[r][t] + ghs[r][t])));
            const float z  = 1.f / (1.f + expf(-(gis[r][128 + t] + ghs[r][128 + t])));
            const float nn = tanhf(gis[r][256 + t] + rg * ghs[r][256 + t]);
            const float hn = (1.f - z) * nn + z * h0_s[r][t];
            hn_s[r][t] = hn;
            out[BATCH * 6 + (img0 + r) * 128 + t] = hn;
        }
    }
    __syncthreads();

    if (t < 48) {
        const int r = t / 6, j = t - r * 6;
        float acc = head_b[j];
        const float* wrow = head_w + j * 128;
        for (int k = 0; k < 128; ++k) acc = fmaf(hn_s[r][k], wrow[k], acc);
        out[(img0 + r) * 6 + j] = acc;
    }
}

extern "C" void kernel_launch(void* const* d_in, const int* in_sizes, int n_in,
                              void* d_out, int out_size, void* d_ws, size_t ws_size,
                              hipStream_t stream) {
    const float* board = (const float*)d_in[0];
    const float* h     = (const float*)d_in[1];
    const int*   atok  = (const int*)d_in[2];
    const int*   uidx  = (const int*)d_in[3];
    const float* w1 = (const float*)d_in[4];
    const float* b1 = (const float*)d_in[5];
    const float* w2 = (const float*)d_in[6];
    const float* b2 = (const float*)d_in[7];
    const float* w3 = (const float*)d_in[8];
    const float* b3 = (const float*)d_in[9];
    const float* w4 = (const float*)d_in[10];
    const float* b4 = (const float*)d_in[11];
    const float* pw = (const float*)d_in[12];
    const float* pb = (const float*)d_in[13];
    const float* emb  = (const float*)d_in[14];
    const float* w_ih = (const float*)d_in[15];
    const float* w_hh = (const float*)d_in[16];
    const float* b_ih = (const float*)d_in[17];
    const float* b_hh = (const float*)d_in[18];
    const float* head_w = (const float*)d_in[19];
    const float* head_b = (const float*)d_in[20];
    float* out = (float*)d_out;
    __hip_bfloat16* wb = (__hip_bfloat16*)d_ws;

    float* bf = out + BATCH * 6;
    prepack_weights<<<(WB_TOTAL + 255) / 256, 256, 0, stream>>>(w1, w2, w3, w4, wb);
    cnn_fused_kernel<<<BATCH, 512, 0, stream>>>(board, b1, b2, b3, b4,
                                                pw, pb, wb, bf);
    gru_kernel<<<BATCH / 8, 384, 0, stream>>>(h, atok, uidx, emb, w_ih, w_hh,
                                              b_ih, b_hh, head_w, head_b, out);
}

// Round 18
// 214.797 us; speedup vs baseline: 1.7731x; 1.4349x over previous
//
#include <hip/hip_runtime.h>
#include <hip/hip_bf16.h>

#define BATCH 4096

typedef __attribute__((ext_vector_type(8))) short short8;
typedef __attribute__((ext_vector_type(16))) float f32x16;

// ---------------- d_ws layout (bf16 elems): weights only ----------------
#define WB1_ELEM 0
#define WB2_ELEM 512
#define WB3_ELEM 5120
#define WB4_ELEM 23552
#define WB_TOTAL 97280

// ---------------- fused-kernel LDS layout (bytes) ----------------
// sb    @0     : padded board bf16 [34][34]  2312 (pad 2320)
// a1band@2320  : 17 rows x 32 cols x 32B, swz key=((col>>2)&1)<<4  17408
// zs1   @19728 : 64B zero slot (conv2 OOB reads)
// a2    @19792 : borderless 16x16 px * 64B, swz key=((r+2c)&3)<<4  16384
// zs2   @36176 : 64B zero slot (conv3 OOB reads)  -> total 36240 (4 blk/CU)
// a3    @0     : 8x8 px * 128B, swz key=((r+2c)&7)<<4 (overlaps sb/a1band)
// zs3   @8192  : 128B zero slot;  meanv @8320 : f32[128]
#define A1_OFF 2320
#define ZS1_OFF 19728
#define A2_OFF 19792
#define ZS2_OFF 36176
#define SMEM_F 36240
#define ZS3_REL 8192
#define MEANV_OFF 8320

static __device__ __forceinline__ unsigned pack2(float a, float b) {
    __hip_bfloat16 lo = __float2bfloat16(a), hi = __float2bfloat16(b);
    unsigned short ul = *(unsigned short*)&lo, uh = *(unsigned short*)&hi;
    return ((unsigned)uh << 16) | ul;
}

static __device__ __forceinline__ void store_bf16(void* p, float v) {
    __hip_bfloat16 b = __float2bfloat16(v);
    *(unsigned short*)p = *(unsigned short*)&b;
}

// ---------------------------------------------------------------------------
// Weight repack (unchanged layouts).
// ---------------------------------------------------------------------------
__global__ void prepack_weights(const float* __restrict__ w1,
                                const float* __restrict__ w2,
                                const float* __restrict__ w3,
                                const float* __restrict__ w4,
                                __hip_bfloat16* __restrict__ wb) {
    int g = blockIdx.x * 256 + threadIdx.x;
    if (g < 512) {
        int oc = g >> 4, k = g & 15;
        float v = (oc < 16 && k < 9) ? w1[oc * 9 + k] : 0.f;
        wb[g] = __float2bfloat16(v);
    } else if (g < WB3_ELEM) {
        int gg = g - WB2_ELEM;
        int oc = gg / 144, r = gg - oc * 144, tap = r >> 4, ic = r & 15;
        wb[g] = __float2bfloat16(w2[oc * 144 + ic * 9 + tap]);
    } else if (g < WB4_ELEM) {
        int gg = g - WB3_ELEM;
        int oc = gg / 288, r = gg - oc * 288, tap = r >> 5, ic = r & 31;
        wb[g] = __float2bfloat16(w3[oc * 288 + ic * 9 + tap]);
    } else if (g < WB_TOTAL) {
        int gg = g - WB4_ELEM;
        int oc = gg / 576, r = gg - oc * 576, tap = r >> 6, ic = r & 63;
        wb[g] = __float2bfloat16(w4[oc * 576 + ic * 9 + tap]);
    }
}

// ---------------------------------------------------------------------------
// Fused CNN, 256 threads, banded conv1/conv2 -> LDS 36.2 KB -> 4 blocks/CU.
// ---------------------------------------------------------------------------
__global__ __launch_bounds__(256, 4) void cnn_fused_kernel(
    const float* __restrict__ board,
    const float* __restrict__ b1, const float* __restrict__ b2,
    const float* __restrict__ b3, const float* __restrict__ b4,
    const float* __restrict__ pw, const float* __restrict__ pb,
    const __hip_bfloat16* __restrict__ wb,
    float* __restrict__ bf_out)
{
    __shared__ alignas(16) char smem[SMEM_F];
    unsigned short* sbu = (unsigned short*)smem;
    char* a1b = smem + A1_OFF;
    char* a3b = smem;                       // overlaps dead sb/a1band later
    float* meanv = (float*)(smem + MEANV_OFF);

    const int t = threadIdx.x;
    const int img = blockIdx.x;
    const int w = t >> 6;                   // wave 0..3
    const int l = t & 63;
    const int n = l & 31;
    const int h = l >> 5;

    const char* wb3 = (const char*)(wb + WB3_ELEM);
    const char* wb4 = (const char*)(wb + WB4_ELEM);

    // ---- P0: zero sb borders + zs1/zs2 ----
    {
        if (t < 132) {
            int i = t, row, col;
            if (i < 34)       { row = 0;  col = i; }
            else if (i < 68)  { row = 33; col = i - 34; }
            else if (i < 100) { row = i - 68 + 1;  col = 0; }
            else              { row = i - 100 + 1; col = 33; }
            sbu[row * 34 + col] = 0;
        }
        uint4 z; z.x = z.y = z.z = z.w = 0u;
        if (t >= 136 && t < 140) ((uint4*)(smem + ZS1_OFF))[t - 136] = z;
        else if (t >= 140 && t < 144) ((uint4*)(smem + ZS2_OFF))[t - 140] = z;
    }
    __syncthreads();

    // ---- P1: load board (f32 -> bf16, padded interior) ----
    {
        float4 v = ((const float4*)board)[img * 256 + t];
        const int p0 = t * 4;
        const int row = (p0 >> 5) + 1, col = (p0 & 31) + 1;
        unsigned short* d = sbu + row * 34 + col;
        __hip_bfloat16 x0 = __float2bfloat16(v.x), x1 = __float2bfloat16(v.y);
        __hip_bfloat16 x2 = __float2bfloat16(v.z), x3 = __float2bfloat16(v.w);
        d[0] = *(unsigned short*)&x0; d[1] = *(unsigned short*)&x1;
        d[2] = *(unsigned short*)&x2; d[3] = *(unsigned short*)&x3;
    }
    __syncthreads();

    // ---- P2/P3 banded: conv1 (17-row band) then conv2 (8 pooled rows) ----
#pragma unroll 1
    for (int band = 0; band < 2; ++band) {
        const int base = band * 15;          // band A rows 0..16, B rows 15..31

        // conv1 (MFMA, taps as K, weights as A): relu -> a1band (swz)
        {
            const short8 A1 = *(const short8*)((const char*)wb + (n * 16 + h * 8) * 2);
            float b1s[8];
#pragma unroll
            for (int r = 0; r < 8; ++r) b1s[r] = b1[(r & 3) + 8 * (r >> 2) + 4 * h];
            const unsigned* sbw = (const unsigned*)smem;
#pragma unroll 1
            for (int yi = 0; yi < 5; ++yi) {
                if (yi == 4 && w != 0) break;              // extra row on wave 0
                const int yg = (yi < 4) ? (base + 4 * w + yi) : (base + 16);
                unsigned short c[3][3];
#pragma unroll
                for (int dy = 0; dy < 3; ++dy) {
                    const int sbase = (yg + dy) * 17 + (n >> 1);
                    const unsigned w0 = sbw[sbase], w1v = sbw[sbase + 1];
                    if (n & 1) {
                        c[dy][0] = (unsigned short)(w0 >> 16);
                        c[dy][1] = (unsigned short)(w1v & 0xffff);
                        c[dy][2] = (unsigned short)(w1v >> 16);
                    } else {
                        c[dy][0] = (unsigned short)(w0 & 0xffff);
                        c[dy][1] = (unsigned short)(w0 >> 16);
                        c[dy][2] = (unsigned short)(w1v & 0xffff);
                    }
                }
                short8 Bv;
                if (h == 0) {
                    Bv[0] = (short)c[0][0]; Bv[1] = (short)c[0][1]; Bv[2] = (short)c[0][2];
                    Bv[3] = (short)c[1][0]; Bv[4] = (short)c[1][1]; Bv[5] = (short)c[1][2];
                    Bv[6] = (short)c[2][0]; Bv[7] = (short)c[2][1];
                } else {
                    Bv = (short8)0;
                    Bv[0] = (short)c[2][2];
                }
                f32x16 acc = __builtin_amdgcn_mfma_f32_32x32x16_bf16(A1, Bv, (f32x16)0.0f, 0, 0, 0);
                float v8[8];
#pragma unroll
                for (int r = 0; r < 8; ++r) v8[r] = fmaxf(acc[r] + b1s[r], 0.f);
                const int key = ((n >> 2) & 1) << 4;
                char* dst = a1b + ((yg - base) * 32 + n) * 32;
                uint2 u0, u1;
                u0.x = pack2(v8[0], v8[1]); u0.y = pack2(v8[2], v8[3]);
                u1.x = pack2(v8[4], v8[5]); u1.y = pack2(v8[6], v8[7]);
                *(uint2*)(dst + ((h * 8) ^ key)) = u0;
                *(uint2*)(dst + ((h * 8 + 16) ^ key)) = u1;
            }
        }
        __syncthreads();

        // conv2 (pixels as A, predicated band reads): relu + pool -> a2
        {
            const char* wb2 = (const char*)(wb + WB2_ELEM);
            short8 Bw[9];
#pragma unroll
            for (int tp = 0; tp < 9; ++tp)
                Bw[tp] = *(const short8*)(wb2 + (n * 144 + tp * 16 + h * 8) * 2);
            const float biasv = b2[n];
            const int y_off = 2 * ((n >> 2) & 1) + ((n >> 1) & 1);
            const int x_off = 2 * ((n >> 3) & 3) + (n & 1);
            const int py_base = 8 * band + 2 * w;     // two pooled rows
            const int yb = 16 * band + 4 * w + y_off; // pre-pool global row

#pragma unroll 1
            for (int pxh = 0; pxh < 2; ++pxh) {
                const int x0 = 16 * pxh + x_off;
                f32x16 acc0 = (f32x16)0.0f, acc1 = (f32x16)0.0f;
#pragma unroll
                for (int tp = 0; tp < 9; ++tp) {
                    const int dy = tp / 3, dx = tp - 3 * dy;
                    const int lr = yb + dy - 1 - base;       // band-local row
                    const int c0 = x0 + dx - 1, c1 = x0 + 8 + dx - 1;
                    const bool okr = (unsigned)lr < 17u;
                    const int off0 = (okr && (unsigned)c0 < 32u)
                        ? (A1_OFF + (lr * 32 + c0) * 32 + ((h * 16) ^ (((c0 >> 2) & 1) << 4)))
                        : (ZS1_OFF + h * 16);
                    const int off1 = (okr && (unsigned)c1 < 32u)
                        ? (A1_OFF + (lr * 32 + c1) * 32 + ((h * 16) ^ (((c1 >> 2) & 1) << 4)))
                        : (ZS1_OFF + h * 16);
                    short8 A0 = *(const short8*)(smem + off0);
                    short8 A1v = *(const short8*)(smem + off1);
                    acc0 = __builtin_amdgcn_mfma_f32_32x32x16_bf16(A0, Bw[tp], acc0, 0, 0, 0);
                    acc1 = __builtin_amdgcn_mfma_f32_32x32x16_bf16(A1v, Bw[tp], acc1, 0, 0, 0);
                }
                const int py = py_base + h;
#pragma unroll
                for (int e = 0; e < 2; ++e) {
                    const f32x16 acc = e ? acc1 : acc0;
                    const int pxb = 2 * pxh + e;
#pragma unroll
                    for (int j = 0; j < 4; ++j) {
                        float v = fmaxf(fmaxf(acc[4 * j], acc[4 * j + 1]),
                                        fmaxf(acc[4 * j + 2], acc[4 * j + 3]));
                        v = fmaxf(v + biasv, 0.f);
                        const int px = 4 * pxb + j;
                        const int key = (py + 2 * px) & 3;
                        store_bf16(smem + A2_OFF + (py * 16 + px) * 64 +
                                   ((((n >> 3) ^ key) & 3) << 4) + ((n * 2) & 15), v);
                    }
                }
            }
        }
        __syncthreads();
    }

    // ---- P4: zero zs3 (sb/a1band region now dead) ----
    {
        uint4 z; z.x = z.y = z.z = z.w = 0u;
        if (t < 8) ((uint4*)(a3b + ZS3_REL))[t] = z;
    }
    __syncthreads();

    // ---- P5: conv3 (pixels as A): 32->64, relu + in-lane pool -> a3 ----
    {
        const int y_off = 2 * ((n >> 2) & 1) + ((n >> 1) & 1);
        const int x_off = 2 * ((n >> 3) & 3) + (n & 1);
        const int y_in = 4 * w + y_off;          // pre-pool row 0..15
        f32x16 acc00 = (f32x16)0.0f, acc01 = (f32x16)0.0f;  // [pxb][ocb]
        f32x16 acc10 = (f32x16)0.0f, acc11 = (f32x16)0.0f;
#pragma unroll
        for (int step = 0; step < 18; ++step) {
            const int tp = step >> 1, kh = step & 1;
            const int dy = tp / 3, dx = tp - 3 * dy;
            short8 B0 = *(const short8*)(wb3 + ((n)      * 288 + tp * 32 + kh * 16 + h * 8) * 2);
            short8 B1 = *(const short8*)(wb3 + ((32 + n) * 288 + tp * 32 + kh * 16 + h * 8) * 2);
            const int row_u = y_in + dy - 1;
            const int col0 = x_off + dx - 1;
            const int col1 = col0 + 8;
            const int sbase = kh * 32 + h * 16;
            const bool okr = (unsigned)row_u < 16u;
            const int off0 = (okr && (unsigned)col0 < 16u)
                ? (A2_OFF + row_u * 1024 + col0 * 64 + (sbase ^ (((row_u + 2 * col0) & 3) << 4)))
                : (ZS2_OFF + sbase);
            const int off1 = (okr && (unsigned)col1 < 16u)
                ? (A2_OFF + row_u * 1024 + col1 * 64 + (sbase ^ (((row_u + 2 * col1) & 3) << 4)))
                : (ZS2_OFF + sbase);
            short8 A0 = *(const short8*)(smem + off0);
            short8 A1v = *(const short8*)(smem + off1);
            acc00 = __builtin_amdgcn_mfma_f32_32x32x16_bf16(A0, B0, acc00, 0, 0, 0);
            acc01 = __builtin_amdgcn_mfma_f32_32x32x16_bf16(A0, B1, acc01, 0, 0, 0);
            acc10 = __builtin_amdgcn_mfma_f32_32x32x16_bf16(A1v, B0, acc10, 0, 0, 0);
            acc11 = __builtin_amdgcn_mfma_f32_32x32x16_bf16(A1v, B1, acc11, 0, 0, 0);
        }
        const int py = 2 * w + h;                 // pooled row 0..7
#pragma unroll
        for (int e = 0; e < 4; ++e) {
            const f32x16 acc = (e == 0) ? acc00 : (e == 1) ? acc01 : (e == 2) ? acc10 : acc11;
            const int pxb = e >> 1, ocb = e & 1;
            const float biasv = b3[32 * ocb + n];
#pragma unroll
            for (int j = 0; j < 4; ++j) {
                float v = fmaxf(fmaxf(acc[4 * j], acc[4 * j + 1]),
                                fmaxf(acc[4 * j + 2], acc[4 * j + 3]));
                v = fmaxf(v + biasv, 0.f);
                const int px = 4 * pxb + j;       // pooled col 0..7
                const int byte_in = ocb * 64 + n * 2;
                const int key3 = (py + 2 * px) & 7;
                store_bf16(a3b + (py * 8 + px) * 128 +
                           ((((byte_in >> 4) ^ key3) << 4) | (byte_in & 15)), v);
            }
        }
    }
    __syncthreads();

    // ---- P6: conv4 (pixels as A): 64->128, relu + in-lane avg -> meanv ----
    {
        const int x4 = n & 7, y4 = (n >> 3) & 3;
        f32x16 aE0 = (f32x16)0.0f, aO0 = (f32x16)0.0f;   // m-tile 0, kc parity
        f32x16 aE1 = (f32x16)0.0f, aO1 = (f32x16)0.0f;   // m-tile 1
#pragma unroll
        for (int dy = 0; dy < 3; ++dy)
#pragma unroll
            for (int dx = 0; dx < 3; ++dx) {
                const int row0 = y4 + dy - 1;            // m0 row, m1 = +4
                const int col_u = x4 + dx - 1;
                const bool okc = (unsigned)col_u < 8u;
                const bool ok0 = okc && ((unsigned)row0 < 8u);
                const bool ok1 = okc && ((unsigned)(row0 + 4) < 8u);
#pragma unroll
                for (int kc = 0; kc < 4; ++kc) {
                    const int s4 = kc * 32 + h * 16;
                    const int off0 = ok0
                        ? ((row0 * 8 + col_u) * 128 + (s4 ^ (((row0 + 2 * col_u) & 7) << 4)))
                        : (ZS3_REL + s4);
                    const int off1 = ok1
                        ? (((row0 + 4) * 8 + col_u) * 128 + (s4 ^ (((row0 + 4 + 2 * col_u) & 7) << 4)))
                        : (ZS3_REL + s4);
                    short8 B = *(const short8*)(wb4 + ((32 * w + n) * 576 + (dy * 3 + dx) * 64 + kc * 16 + h * 8) * 2);
                    short8 A0 = *(const short8*)(a3b + off0);
                    short8 A1v = *(const short8*)(a3b + off1);
                    if (kc & 1) {
                        aO0 = __builtin_amdgcn_mfma_f32_32x32x16_bf16(A0, B, aO0, 0, 0, 0);
                        aO1 = __builtin_amdgcn_mfma_f32_32x32x16_bf16(A1v, B, aO1, 0, 0, 0);
                    } else {
                        aE0 = __builtin_amdgcn_mfma_f32_32x32x16_bf16(A0, B, aE0, 0, 0, 0);
                        aE1 = __builtin_amdgcn_mfma_f32_32x32x16_bf16(A1v, B, aE1, 0, 0, 0);
                    }
                }
            }
        const float biasv = b4[32 * w + n];
        float s = 0.f;
#pragma unroll
        for (int r = 0; r < 16; ++r) {
            s += fmaxf(aE0[r] + aO0[r] + biasv, 0.f);
            s += fmaxf(aE1[r] + aO1[r] + biasv, 0.f);
        }
        s += __shfl_xor(s, 32);
        if (l < 32) meanv[32 * w + l] = s * (1.f / 64.f);
    }
    __syncthreads();

    // ---- P7: proj (VALU, 256 threads, k-split) ----
    {
        const int o = t >> 1, kh = t & 1;
        const float* wrow = pw + o * 128 + kh * 64;
        const float* mv = meanv + kh * 64;
        float acc = 0.f;
        for (int k = 0; k < 64; ++k) acc = fmaf(mv[k], wrow[k], acc);
        acc += __shfl_xor(acc, 1);
        if (kh == 0) bf_out[img * 128 + o] = acc + pb[o];
    }
}

// ---------------------------------------------------------------------------
// Kernel C: GRU step + head (unchanged).
// ---------------------------------------------------------------------------
__global__ __launch_bounds__(384) void gru_kernel(
    const float* __restrict__ hin,
    const int* __restrict__ atok, const int* __restrict__ uidx,
    const float* __restrict__ emb,
    const float* __restrict__ w_ih, const float* __restrict__ w_hh,
    const float* __restrict__ b_ih, const float* __restrict__ b_hh,
    const float* __restrict__ head_w, const float* __restrict__ head_b,
    float* __restrict__ out)
{
    const int img0 = blockIdx.x * 8;
    const int t = threadIdx.x;
    __shared__ float xin_s[8][168];
    __shared__ float h0_s[8][128];
    __shared__ float gis[8][384];
    __shared__ float ghs[8][384];
    __shared__ float hn_s[8][128];
    const float* bf = out + BATCH * 6;

    for (int idx = t; idx < 8 * 168; idx += 384) {
        const int r = idx / 168, k = idx - r * 168;
        const int row = img0 + r;
        float v;
        if (k < 128)      v = bf[row * 128 + k];
        else if (k < 136) v = (float)((atok[row] >> (k - 128)) & 1);
        else              v = emb[uidx[row] * 32 + (k - 136)];
        xin_s[r][k] = v;
    }
    for (int idx = t; idx < 8 * 128; idx += 384) {
        const int r = idx >> 7, k = idx & 127;
        h0_s[r][k] = hin[(img0 + r) * 128 + k];
    }
    __syncthreads();

    {
        const int o = t;
        float gi[8], gh[8];
        const float bi = b_ih[o], bh = b_hh[o];
#pragma unroll
        for (int r = 0; r < 8; ++r) { gi[r] = bi; gh[r] = bh; }
        const float* wi = w_ih + o * 168;
        const float* wh = w_hh + o * 128;
        for (int k = 0; k < 128; ++k) {
            const float wv = wi[k];
            const float wvh = wh[k];
#pragma unroll
            for (int r = 0; r < 8; ++r) {
                gi[r] = fmaf(wv, xin_s[r][k], gi[r]);
                gh[r] = fmaf(wvh, h0_s[r][k], gh[r]);
            }
        }
        for (int k = 128; k < 168; ++k) {
            const float wv = wi[k];
#pragma unroll
            for (int r = 0; r < 8; ++r) gi[r] = fmaf(wv, xin_s[r][k], gi[r]);
        }
#pragma unroll
        for (int r = 0; r < 8; ++r) { gis[r][o] = gi[r]; ghs[r][o] = gh[r]; }
    }
    __syncthreads();

    if (t < 128) {
#pragma unroll
        for (int r = 0; r < 8; ++r) {
            const float rg = 1.f / (1.f + expf(-(gis[r][t] + ghs[r][t])));
            const float z  = 1.f / (1.f + expf(-(gis[r][128 + t] + ghs[r][128 + t])));
            const float nn = tanhf(gis[r][256 + t] + rg * ghs[r][256 + t]);
            const float hn = (1.f - z) * nn + z * h0_s[r][t];
            hn_s[r][t] = hn;
            out[BATCH * 6 + (img0 + r) * 128 + t] = hn;
        }
    }
    __syncthreads();

    if (t < 48) {
        const int r = t / 6, j = t - r * 6;
        float acc = head_b[j];
        const float* wrow = head_w + j * 128;
        for (int k = 0; k < 128; ++k) acc = fmaf(hn_s[r][k], wrow[k], acc);
        out[(img0 + r) * 6 + j] = acc;
    }
}

extern "C" void kernel_launch(void* const* d_in, const int* in_sizes, int n_in,
                              void* d_out, int out_size, void* d_ws, size_t ws_size,
                              hipStream_t stream) {
    const float* board = (const float*)d_in[0];
    const float* h     = (const float*)d_in[1];
    const int*   atok  = (const int*)d_in[2];
    const int*   uidx  = (const int*)d_in[3];
    const float* w1 = (const float*)d_in[4];
    const float* b1 = (const float*)d_in[5];
    const float* w2 = (const float*)d_in[6];
    const float* b2 = (const float*)d_in[7];
    const float* w3 = (const float*)d_in[8];
    const float* b3 = (const float*)d_in[9];
    const float* w4 = (const float*)d_in[10];
    const float* b4 = (const float*)d_in[11];
    const float* pw = (const float*)d_in[12];
    const float* pb = (const float*)d_in[13];
    const float* emb  = (const float*)d_in[14];
    const float* w_ih = (const float*)d_in[15];
    const float* w_hh = (const float*)d_in[16];
    const float* b_ih = (const float*)d_in[17];
    const float* b_hh = (const float*)d_in[18];
    const float* head_w = (const float*)d_in[19];
    const float* head_b = (const float*)d_in[20];
    float* out = (float*)d_out;
    __hip_bfloat16* wb = (__hip_bfloat16*)d_ws;

    float* bf = out + BATCH * 6;
    prepack_weights<<<(WB_TOTAL + 255) / 256, 256, 0, stream>>>(w1, w2, w3, w4, wb);
    cnn_fused_kernel<<<BATCH, 256, 0, stream>>>(board, b1, b2, b3, b4,
                                                pw, pb, wb, bf);
    gru_kernel<<<BATCH / 8, 384, 0, stream>>>(h, atok, uidx, emb, w_ih, w_hh,
                                              b_ih, b_hh, head_w, head_b, out);
}

// Round 19
// 191.738 us; speedup vs baseline: 1.9863x; 1.1203x over previous
//
#include <hip/hip_runtime.h>
#include <hip/hip_bf16.h>

#define BATCH 4096

typedef __attribute__((ext_vector_type(8))) short short8;
typedef __attribute__((ext_vector_type(16))) float f32x16;

// ---------------- d_ws layout (bf16 elems): weights only ----------------
#define WB1_ELEM 0
#define WB2_ELEM 512
#define WB3_ELEM 5120
#define WB4_ELEM 23552
#define WB_TOTAL 97280

// ---------------- fused-kernel LDS layout (bytes) ----------------
#define A1_OFF 2320
#define ZS1_OFF 19728
#define A2_OFF 19792
#define ZS2_OFF 36176
#define SMEM_F 36240
#define ZS3_REL 8192
#define MEANV_OFF 8320

static __device__ __forceinline__ unsigned pack2(float a, float b) {
    __hip_bfloat16 lo = __float2bfloat16(a), hi = __float2bfloat16(b);
    unsigned short ul = *(unsigned short*)&lo, uh = *(unsigned short*)&hi;
    return ((unsigned)uh << 16) | ul;
}

static __device__ __forceinline__ void store_bf16(void* p, float v) {
    __hip_bfloat16 b = __float2bfloat16(v);
    *(unsigned short*)p = *(unsigned short*)&b;
}

// ---------------------------------------------------------------------------
// Weight repack (unchanged layouts).
// ---------------------------------------------------------------------------
__global__ void prepack_weights(const float* __restrict__ w1,
                                const float* __restrict__ w2,
                                const float* __restrict__ w3,
                                const float* __restrict__ w4,
                                __hip_bfloat16* __restrict__ wb) {
    int g = blockIdx.x * 256 + threadIdx.x;
    if (g < 512) {
        int oc = g >> 4, k = g & 15;
        float v = (oc < 16 && k < 9) ? w1[oc * 9 + k] : 0.f;
        wb[g] = __float2bfloat16(v);
    } else if (g < WB3_ELEM) {
        int gg = g - WB2_ELEM;
        int oc = gg / 144, r = gg - oc * 144, tap = r >> 4, ic = r & 15;
        wb[g] = __float2bfloat16(w2[oc * 144 + ic * 9 + tap]);
    } else if (g < WB4_ELEM) {
        int gg = g - WB3_ELEM;
        int oc = gg / 288, r = gg - oc * 288, tap = r >> 5, ic = r & 31;
        wb[g] = __float2bfloat16(w3[oc * 288 + ic * 9 + tap]);
    } else if (g < WB_TOTAL) {
        int gg = g - WB4_ELEM;
        int oc = gg / 576, r = gg - oc * 576, tap = r >> 6, ic = r & 63;
        wb[g] = __float2bfloat16(w4[oc * 576 + ic * 9 + tap]);
    }
}

// ---------------------------------------------------------------------------
// Fused CNN, 256 threads, banded conv1/conv2 -> LDS 36.2 KB -> 4 blocks/CU.
// (verbatim R18)
// ---------------------------------------------------------------------------
__global__ __launch_bounds__(256, 4) void cnn_fused_kernel(
    const float* __restrict__ board,
    const float* __restrict__ b1, const float* __restrict__ b2,
    const float* __restrict__ b3, const float* __restrict__ b4,
    const float* __restrict__ pw, const float* __restrict__ pb,
    const __hip_bfloat16* __restrict__ wb,
    float* __restrict__ bf_out)
{
    __shared__ alignas(16) char smem[SMEM_F];
    unsigned short* sbu = (unsigned short*)smem;
    char* a1b = smem + A1_OFF;
    char* a3b = smem;
    float* meanv = (float*)(smem + MEANV_OFF);

    const int t = threadIdx.x;
    const int img = blockIdx.x;
    const int w = t >> 6;
    const int l = t & 63;
    const int n = l & 31;
    const int h = l >> 5;

    const char* wb3 = (const char*)(wb + WB3_ELEM);
    const char* wb4 = (const char*)(wb + WB4_ELEM);

    // ---- P0: zero sb borders + zs1/zs2 ----
    {
        if (t < 132) {
            int i = t, row, col;
            if (i < 34)       { row = 0;  col = i; }
            else if (i < 68)  { row = 33; col = i - 34; }
            else if (i < 100) { row = i - 68 + 1;  col = 0; }
            else              { row = i - 100 + 1; col = 33; }
            sbu[row * 34 + col] = 0;
        }
        uint4 z; z.x = z.y = z.z = z.w = 0u;
        if (t >= 136 && t < 140) ((uint4*)(smem + ZS1_OFF))[t - 136] = z;
        else if (t >= 140 && t < 144) ((uint4*)(smem + ZS2_OFF))[t - 140] = z;
    }
    __syncthreads();

    // ---- P1: load board (f32 -> bf16, padded interior) ----
    {
        float4 v = ((const float4*)board)[img * 256 + t];
        const int p0 = t * 4;
        const int row = (p0 >> 5) + 1, col = (p0 & 31) + 1;
        unsigned short* d = sbu + row * 34 + col;
        __hip_bfloat16 x0 = __float2bfloat16(v.x), x1 = __float2bfloat16(v.y);
        __hip_bfloat16 x2 = __float2bfloat16(v.z), x3 = __float2bfloat16(v.w);
        d[0] = *(unsigned short*)&x0; d[1] = *(unsigned short*)&x1;
        d[2] = *(unsigned short*)&x2; d[3] = *(unsigned short*)&x3;
    }
    __syncthreads();

    // ---- P2/P3 banded: conv1 (17-row band) then conv2 (8 pooled rows) ----
#pragma unroll 1
    for (int band = 0; band < 2; ++band) {
        const int base = band * 15;

        {
            const short8 A1 = *(const short8*)((const char*)wb + (n * 16 + h * 8) * 2);
            float b1s[8];
#pragma unroll
            for (int r = 0; r < 8; ++r) b1s[r] = b1[(r & 3) + 8 * (r >> 2) + 4 * h];
            const unsigned* sbw = (const unsigned*)smem;
#pragma unroll 1
            for (int yi = 0; yi < 5; ++yi) {
                if (yi == 4 && w != 0) break;
                const int yg = (yi < 4) ? (base + 4 * w + yi) : (base + 16);
                unsigned short c[3][3];
#pragma unroll
                for (int dy = 0; dy < 3; ++dy) {
                    const int sbase = (yg + dy) * 17 + (n >> 1);
                    const unsigned w0 = sbw[sbase], w1v = sbw[sbase + 1];
                    if (n & 1) {
                        c[dy][0] = (unsigned short)(w0 >> 16);
                        c[dy][1] = (unsigned short)(w1v & 0xffff);
                        c[dy][2] = (unsigned short)(w1v >> 16);
                    } else {
                        c[dy][0] = (unsigned short)(w0 & 0xffff);
                        c[dy][1] = (unsigned short)(w0 >> 16);
                        c[dy][2] = (unsigned short)(w1v & 0xffff);
                    }
                }
                short8 Bv;
                if (h == 0) {
                    Bv[0] = (short)c[0][0]; Bv[1] = (short)c[0][1]; Bv[2] = (short)c[0][2];
                    Bv[3] = (short)c[1][0]; Bv[4] = (short)c[1][1]; Bv[5] = (short)c[1][2];
                    Bv[6] = (short)c[2][0]; Bv[7] = (short)c[2][1];
                } else {
                    Bv = (short8)0;
                    Bv[0] = (short)c[2][2];
                }
                f32x16 acc = __builtin_amdgcn_mfma_f32_32x32x16_bf16(A1, Bv, (f32x16)0.0f, 0, 0, 0);
                float v8[8];
#pragma unroll
                for (int r = 0; r < 8; ++r) v8[r] = fmaxf(acc[r] + b1s[r], 0.f);
                const int key = ((n >> 2) & 1) << 4;
                char* dst = a1b + ((yg - base) * 32 + n) * 32;
                uint2 u0, u1;
                u0.x = pack2(v8[0], v8[1]); u0.y = pack2(v8[2], v8[3]);
                u1.x = pack2(v8[4], v8[5]); u1.y = pack2(v8[6], v8[7]);
                *(uint2*)(dst + ((h * 8) ^ key)) = u0;
                *(uint2*)(dst + ((h * 8 + 16) ^ key)) = u1;
            }
        }
        __syncthreads();

        {
            const char* wb2 = (const char*)(wb + WB2_ELEM);
            short8 Bw[9];
#pragma unroll
            for (int tp = 0; tp < 9; ++tp)
                Bw[tp] = *(const short8*)(wb2 + (n * 144 + tp * 16 + h * 8) * 2);
            const float biasv = b2[n];
            const int y_off = 2 * ((n >> 2) & 1) + ((n >> 1) & 1);
            const int x_off = 2 * ((n >> 3) & 3) + (n & 1);
            const int py_base = 8 * band + 2 * w;
            const int yb = 16 * band + 4 * w + y_off;

#pragma unroll 1
            for (int pxh = 0; pxh < 2; ++pxh) {
                const int x0 = 16 * pxh + x_off;
                f32x16 acc0 = (f32x16)0.0f, acc1 = (f32x16)0.0f;
#pragma unroll
                for (int tp = 0; tp < 9; ++tp) {
                    const int dy = tp / 3, dx = tp - 3 * dy;
                    const int lr = yb + dy - 1 - base;
                    const int c0 = x0 + dx - 1, c1 = x0 + 8 + dx - 1;
                    const bool okr = (unsigned)lr < 17u;
                    const int off0 = (okr && (unsigned)c0 < 32u)
                        ? (A1_OFF + (lr * 32 + c0) * 32 + ((h * 16) ^ (((c0 >> 2) & 1) << 4)))
                        : (ZS1_OFF + h * 16);
                    const int off1 = (okr && (unsigned)c1 < 32u)
                        ? (A1_OFF + (lr * 32 + c1) * 32 + ((h * 16) ^ (((c1 >> 2) & 1) << 4)))
                        : (ZS1_OFF + h * 16);
                    short8 A0 = *(const short8*)(smem + off0);
                    short8 A1v = *(const short8*)(smem + off1);
                    acc0 = __builtin_amdgcn_mfma_f32_32x32x16_bf16(A0, Bw[tp], acc0, 0, 0, 0);
                    acc1 = __builtin_amdgcn_mfma_f32_32x32x16_bf16(A1v, Bw[tp], acc1, 0, 0, 0);
                }
                const int py = py_base + h;
#pragma unroll
                for (int e = 0; e < 2; ++e) {
                    const f32x16 acc = e ? acc1 : acc0;
                    const int pxb = 2 * pxh + e;
#pragma unroll
                    for (int j = 0; j < 4; ++j) {
                        float v = fmaxf(fmaxf(acc[4 * j], acc[4 * j + 1]),
                                        fmaxf(acc[4 * j + 2], acc[4 * j + 3]));
                        v = fmaxf(v + biasv, 0.f);
                        const int px = 4 * pxb + j;
                        const int key = (py + 2 * px) & 3;
                        store_bf16(smem + A2_OFF + (py * 16 + px) * 64 +
                                   ((((n >> 3) ^ key) & 3) << 4) + ((n * 2) & 15), v);
                    }
                }
            }
        }
        __syncthreads();
    }

    // ---- P4: zero zs3 ----
    {
        uint4 z; z.x = z.y = z.z = z.w = 0u;
        if (t < 8) ((uint4*)(a3b + ZS3_REL))[t] = z;
    }
    __syncthreads();

    // ---- P5: conv3 ----
    {
        const int y_off = 2 * ((n >> 2) & 1) + ((n >> 1) & 1);
        const int x_off = 2 * ((n >> 3) & 3) + (n & 1);
        const int y_in = 4 * w + y_off;
        f32x16 acc00 = (f32x16)0.0f, acc01 = (f32x16)0.0f;
        f32x16 acc10 = (f32x16)0.0f, acc11 = (f32x16)0.0f;
#pragma unroll
        for (int step = 0; step < 18; ++step) {
            const int tp = step >> 1, kh = step & 1;
            const int dy = tp / 3, dx = tp - 3 * dy;
            short8 B0 = *(const short8*)(wb3 + ((n)      * 288 + tp * 32 + kh * 16 + h * 8) * 2);
            short8 B1 = *(const short8*)(wb3 + ((32 + n) * 288 + tp * 32 + kh * 16 + h * 8) * 2);
            const int row_u = y_in + dy - 1;
            const int col0 = x_off + dx - 1;
            const int col1 = col0 + 8;
            const int sbase = kh * 32 + h * 16;
            const bool okr = (unsigned)row_u < 16u;
            const int off0 = (okr && (unsigned)col0 < 16u)
                ? (A2_OFF + row_u * 1024 + col0 * 64 + (sbase ^ (((row_u + 2 * col0) & 3) << 4)))
                : (ZS2_OFF + sbase);
            const int off1 = (okr && (unsigned)col1 < 16u)
                ? (A2_OFF + row_u * 1024 + col1 * 64 + (sbase ^ (((row_u + 2 * col1) & 3) << 4)))
                : (ZS2_OFF + sbase);
            short8 A0 = *(const short8*)(smem + off0);
            short8 A1v = *(const short8*)(smem + off1);
            acc00 = __builtin_amdgcn_mfma_f32_32x32x16_bf16(A0, B0, acc00, 0, 0, 0);
            acc01 = __builtin_amdgcn_mfma_f32_32x32x16_bf16(A0, B1, acc01, 0, 0, 0);
            acc10 = __builtin_amdgcn_mfma_f32_32x32x16_bf16(A1v, B0, acc10, 0, 0, 0);
            acc11 = __builtin_amdgcn_mfma_f32_32x32x16_bf16(A1v, B1, acc11, 0, 0, 0);
        }
        const int py = 2 * w + h;
#pragma unroll
        for (int e = 0; e < 4; ++e) {
            const f32x16 acc = (e == 0) ? acc00 : (e == 1) ? acc01 : (e == 2) ? acc10 : acc11;
            const int pxb = e >> 1, ocb = e & 1;
            const float biasv = b3[32 * ocb + n];
#pragma unroll
            for (int j = 0; j < 4; ++j) {
                float v = fmaxf(fmaxf(acc[4 * j], acc[4 * j + 1]),
                                fmaxf(acc[4 * j + 2], acc[4 * j + 3]));
                v = fmaxf(v + biasv, 0.f);
                const int px = 4 * pxb + j;
                const int byte_in = ocb * 64 + n * 2;
                const int key3 = (py + 2 * px) & 7;
                store_bf16(a3b + (py * 8 + px) * 128 +
                           ((((byte_in >> 4) ^ key3) << 4) | (byte_in & 15)), v);
            }
        }
    }
    __syncthreads();

    // ---- P6: conv4 ----
    {
        const int x4 = n & 7, y4 = (n >> 3) & 3;
        f32x16 aE0 = (f32x16)0.0f, aO0 = (f32x16)0.0f;
        f32x16 aE1 = (f32x16)0.0f, aO1 = (f32x16)0.0f;
#pragma unroll
        for (int dy = 0; dy < 3; ++dy)
#pragma unroll
            for (int dx = 0; dx < 3; ++dx) {
                const int row0 = y4 + dy - 1;
                const int col_u = x4 + dx - 1;
                const bool okc = (unsigned)col_u < 8u;
                const bool ok0 = okc && ((unsigned)row0 < 8u);
                const bool ok1 = okc && ((unsigned)(row0 + 4) < 8u);
#pragma unroll
                for (int kc = 0; kc < 4; ++kc) {
                    const int s4 = kc * 32 + h * 16;
                    const int off0 = ok0
                        ? ((row0 * 8 + col_u) * 128 + (s4 ^ (((row0 + 2 * col_u) & 7) << 4)))
                        : (ZS3_REL + s4);
                    const int off1 = ok1
                        ? (((row0 + 4) * 8 + col_u) * 128 + (s4 ^ (((row0 + 4 + 2 * col_u) & 7) << 4)))
                        : (ZS3_REL + s4);
                    short8 B = *(const short8*)(wb4 + ((32 * w + n) * 576 + (dy * 3 + dx) * 64 + kc * 16 + h * 8) * 2);
                    short8 A0 = *(const short8*)(a3b + off0);
                    short8 A1v = *(const short8*)(a3b + off1);
                    if (kc & 1) {
                        aO0 = __builtin_amdgcn_mfma_f32_32x32x16_bf16(A0, B, aO0, 0, 0, 0);
                        aO1 = __builtin_amdgcn_mfma_f32_32x32x16_bf16(A1v, B, aO1, 0, 0, 0);
                    } else {
                        aE0 = __builtin_amdgcn_mfma_f32_32x32x16_bf16(A0, B, aE0, 0, 0, 0);
                        aE1 = __builtin_amdgcn_mfma_f32_32x32x16_bf16(A1v, B, aE1, 0, 0, 0);
                    }
                }
            }
        const float biasv = b4[32 * w + n];
        float s = 0.f;
#pragma unroll
        for (int r = 0; r < 16; ++r) {
            s += fmaxf(aE0[r] + aO0[r] + biasv, 0.f);
            s += fmaxf(aE1[r] + aO1[r] + biasv, 0.f);
        }
        s += __shfl_xor(s, 32);
        if (l < 32) meanv[32 * w + l] = s * (1.f / 64.f);
    }
    __syncthreads();

    // ---- P7: proj (VALU, 256 threads, k-split) ----
    {
        const int o = t >> 1, kh = t & 1;
        const float* wrow = pw + o * 128 + kh * 64;
        const float* mv = meanv + kh * 64;
        float acc = 0.f;
        for (int k = 0; k < 64; ++k) acc = fmaf(mv[k], wrow[k], acc);
        acc += __shfl_xor(acc, 1);
        if (kh == 0) bf_out[img * 128 + o] = acc + pb[o];
    }
}

// ---------------------------------------------------------------------------
// Kernel C: GRU step + head, float4-vectorized k-loops.
// ---------------------------------------------------------------------------
__global__ __launch_bounds__(384) void gru_kernel(
    const float* __restrict__ hin,
    const int* __restrict__ atok, const int* __restrict__ uidx,
    const float* __restrict__ emb,
    const float* __restrict__ w_ih, const float* __restrict__ w_hh,
    const float* __restrict__ b_ih, const float* __restrict__ b_hh,
    const float* __restrict__ head_w, const float* __restrict__ head_b,
    float* __restrict__ out)
{
    const int img0 = blockIdx.x * 8;
    const int t = threadIdx.x;
    __shared__ float xin_s[8][176];   // 168 data + 8 zero pad
    __shared__ float h0_s[8][128];
    __shared__ float gis[8][384];
    __shared__ float ghs[8][384];
    __shared__ float hn_s[8][128];
    const float* bf = out + BATCH * 6;

    for (int idx = t; idx < 8 * 176; idx += 384) {
        const int r = idx / 176, k = idx - r * 176;
        const int row = img0 + r;
        float v;
        if (k < 128)      v = bf[row * 128 + k];
        else if (k < 136) v = (float)((atok[row] >> (k - 128)) & 1);
        else if (k < 168) v = emb[uidx[row] * 32 + (k - 136)];
        else              v = 0.f;
        xin_s[r][k] = v;
    }
    for (int idx = t; idx < 8 * 128; idx += 384) {
        const int r = idx >> 7, k = idx & 127;
        h0_s[r][k] = hin[(img0 + r) * 128 + k];
    }
    __syncthreads();

    // gi = xin @ w_ih.T + b_ih ; gh = h0 @ w_hh.T + b_hh  (float4 k-loops)
    {
        const int o = t;
        float gi[8], gh[8];
        const float bi = b_ih[o], bh = b_hh[o];
#pragma unroll
        for (int r = 0; r < 8; ++r) { gi[r] = bi; gh[r] = bh; }
        const float* wi = w_ih + o * 168;       // 672B rows, 16B aligned
        const float* wh = w_hh + o * 128;       // 512B rows, 16B aligned
#pragma unroll 2
        for (int k = 0; k < 168; k += 4) {
            const float4 wv = *(const float4*)(wi + k);
#pragma unroll
            for (int r = 0; r < 8; ++r) {
                const float4 xv = *(const float4*)(&xin_s[r][k]);
                float a = fmaf(wv.x, xv.x, gi[r]);
                a = fmaf(wv.y, xv.y, a);
                a = fmaf(wv.z, xv.z, a);
                gi[r] = fmaf(wv.w, xv.w, a);
            }
        }
#pragma unroll 2
        for (int k = 0; k < 128; k += 4) {
            const float4 wv = *(const float4*)(wh + k);
#pragma unroll
            for (int r = 0; r < 8; ++r) {
                const float4 xv = *(const float4*)(&h0_s[r][k]);
                float a = fmaf(wv.x, xv.x, gh[r]);
                a = fmaf(wv.y, xv.y, a);
                a = fmaf(wv.z, xv.z, a);
                gh[r] = fmaf(wv.w, xv.w, a);
            }
        }
#pragma unroll
        for (int r = 0; r < 8; ++r) { gis[r][o] = gi[r]; ghs[r][o] = gh[r]; }
    }
    __syncthreads();

    if (t < 128) {
#pragma unroll
        for (int r = 0; r < 8; ++r) {
            const float rg = 1.f / (1.f + expf(-(gis[r][t] + ghs[r][t])));
            const float z  = 1.f / (1.f + expf(-(gis[r][128 + t] + ghs[r][128 + t])));
            const float nn = tanhf(gis[r][256 + t] + rg * ghs[r][256 + t]);
            const float hn = (1.f - z) * nn + z * h0_s[r][t];
            hn_s[r][t] = hn;
            out[BATCH * 6 + (img0 + r) * 128 + t] = hn;
        }
    }
    __syncthreads();

    if (t < 48) {
        const int r = t / 6, j = t - r * 6;
        float acc = head_b[j];
        const float* wrow = head_w + j * 128;
        for (int k = 0; k < 128; ++k) acc = fmaf(hn_s[r][k], wrow[k], acc);
        out[(img0 + r) * 6 + j] = acc;
    }
}

extern "C" void kernel_launch(void* const* d_in, const int* in_sizes, int n_in,
                              void* d_out, int out_size, void* d_ws, size_t ws_size,
                              hipStream_t stream) {
    const float* board = (const float*)d_in[0];
    const float* h     = (const float*)d_in[1];
    const int*   atok  = (const int*)d_in[2];
    const int*   uidx  = (const int*)d_in[3];
    const float* w1 = (const float*)d_in[4];
    const float* b1 = (const float*)d_in[5];
    const float* w2 = (const float*)d_in[6];
    const float* b2 = (const float*)d_in[7];
    const float* w3 = (const float*)d_in[8];
    const float* b3 = (const float*)d_in[9];
    const float* w4 = (const float*)d_in[10];
    const float* b4 = (const float*)d_in[11];
    const float* pw = (const float*)d_in[12];
    const float* pb = (const float*)d_in[13];
    const float* emb  = (const float*)d_in[14];
    const float* w_ih = (const float*)d_in[15];
    const float* w_hh = (const float*)d_in[16];
    const float* b_ih = (const float*)d_in[17];
    const float* b_hh = (const float*)d_in[18];
    const float* head_w = (const float*)d_in[19];
    const float* head_b = (const float*)d_in[20];
    float* out = (float*)d_out;
    __hip_bfloat16* wb = (__hip_bfloat16*)d_ws;

    float* bf = out + BATCH * 6;
    prepack_weights<<<(WB_TOTAL + 255) / 256, 256, 0, stream>>>(w1, w2, w3, w4, wb);
    cnn_fused_kernel<<<BATCH, 256, 0, stream>>>(board, b1, b2, b3, b4,
                                                pw, pb, wb, bf);
    gru_kernel<<<BATCH / 8, 384, 0, stream>>>(h, atok, uidx, emb, w_ih, w_hh,
                                              b_ih, b_hh, head_w, head_b, out);
}